// Round 14
// baseline (1262.292 us; speedup 1.0000x reference)
//
#include <hip/hip_runtime.h>
#include <stdint.h>

#define DEV __device__ __forceinline__

constexpr int E_ = 16, M_ = 128, H_ = 2048, I_ = 2048;
constexpr int X_ = 16;            // A*B = 2*8
constexpr int N1 = 2 * I_;        // 4096
constexpr int ROWS = X_ * M_;     // 2048 rows per expert

typedef short bfrag __attribute__((ext_vector_type(8)));   // 8 bf16 (4 VGPRs)
typedef float ffrag __attribute__((ext_vector_type(4)));   // MFMA C/D frag
typedef unsigned short us8 __attribute__((ext_vector_type(8)));

DEV unsigned short f2bf(float f) {
    union { float f; unsigned u; } v; v.f = f;
    unsigned u = v.u;
    u += 0x7fffu + ((u >> 16) & 1u);   // RNE
    return (unsigned short)(u >> 16);
}

DEV void gload16(const void* g, void* lds_wave_base) {
    __builtin_amdgcn_global_load_lds(
        (const __attribute__((address_space(1))) unsigned int*)g,
        (__attribute__((address_space(3))) unsigned int*)lds_wave_base,
        16, 0, 0);
}

DEV void block_bar() {
    asm volatile("" ::: "memory");
    __builtin_amdgcn_s_barrier();
    asm volatile("" ::: "memory");
}

// ---------------- converts ----------------

// dispatched (X,E,M,H) f32 -> a_bf (E, X*M, H) bf16  (token-major per expert)
__global__ __launch_bounds__(256) void convert_a(const float* __restrict__ in,
                                                 unsigned short* __restrict__ outb) {
    const int n4 = X_ * E_ * M_ * H_ / 4;
    int idx = blockIdx.x * 256 + threadIdx.x;
    int stride = gridDim.x * 256;
    for (int f = idx; f < n4; f += stride) {
        float4 v = ((const float4*)in)[f];
        ushort4 o;
        o.x = f2bf(v.x); o.y = f2bf(v.y); o.z = f2bf(v.z); o.w = f2bf(v.w);
        const int c = f & 511;          // float4 within row (H/4 = 512)
        const int row = f >> 9;         // (x,e,m) row
        const int m = row & 127, e = (row >> 7) & 15, x = row >> 11;
        ((ushort4*)outb)[((size_t)(e * ROWS + x * M_ + m) << 9) + c] = o;
    }
}

// gate_up (E,H,4096) fp32 -> b1t (E,4096,H) bf16, de-interleaved.
__global__ __launch_bounds__(256) void convert_b1(const float* __restrict__ gup,
                                                  unsigned short* __restrict__ b1t) {
    const int e = blockIdx.x, h0 = blockIdx.y * 64, n0 = blockIdx.z * 128;
    __shared__ float2 tile2[64][64];   // [h-local][n-pair]
    const float* src = gup + (size_t)e * H_ * N1;
    const int t = threadIdx.x;
#pragma unroll
    for (int i = 0; i < 8; ++i) {
        int idx = i * 1024 + t * 4;
        int r = idx >> 7, c = idx & 127;
        float4 v = *(const float4*)(src + (size_t)(h0 + r) * N1 + n0 + c);
        *(float4*)&tile2[r][c >> 1] = v;   // c%4==0 -> 16B aligned
    }
    __syncthreads();
    const int p = t >> 2;          // local output n-row 0..63
    const int hh = (t & 3) * 16;   // 16 h's per thread
    us8 g0, g1, u0, u1;
#pragma unroll
    for (int k = 0; k < 8; ++k) {
        float2 a = tile2[hh + k][p];
        float2 b = tile2[hh + 8 + k][p];
        g0[k] = f2bf(a.x); u0[k] = f2bf(a.y);
        g1[k] = f2bf(b.x); u1[k] = f2bf(b.y);
    }
    unsigned short* dg = b1t + ((size_t)e * N1 + (n0 >> 1) + p) * H_ + h0 + hh;
    unsigned short* du = b1t + ((size_t)e * N1 + I_ + (n0 >> 1) + p) * H_ + h0 + hh;
    *(us8*)dg = g0; *(us8*)(dg + 8) = g1;
    *(us8*)du = u0; *(us8*)(du + 8) = u1;
}

// down (E,I,H) fp32 -> b2t (E,H,I) bf16
__global__ __launch_bounds__(256) void convert_b2(const float* __restrict__ dwn,
                                                  unsigned short* __restrict__ b2t) {
    const int e = blockIdx.x, i0 = blockIdx.y * 64, h0 = blockIdx.z * 64;
    __shared__ float tile[64][65];
    const float* src = dwn + (size_t)e * I_ * H_;
    const int t = threadIdx.x;
#pragma unroll
    for (int it = 0; it < 4; ++it) {
        int idx = it * 1024 + t * 4;
        int r = idx >> 6, c = idx & 63;
        float4 v = *(const float4*)(src + (size_t)(i0 + r) * H_ + h0 + c);
        tile[r][c] = v.x; tile[r][c + 1] = v.y; tile[r][c + 2] = v.z; tile[r][c + 3] = v.w;
    }
    __syncthreads();
    const int hl = t >> 2, ii = (t & 3) * 16;
    us8 o0, o1;
#pragma unroll
    for (int k = 0; k < 8; ++k) {
        o0[k] = f2bf(tile[ii + k][hl]);
        o1[k] = f2bf(tile[ii + 8 + k][hl]);
    }
    unsigned short* d = b2t + ((size_t)e * H_ + h0 + hl) * I_ + i0 + ii;
    *(us8*)d = o0; *(us8*)(d + 8) = o1;
}

// ---- 256x128 4-wave, BK=32, 2-buf, 2-BLOCKS-PER-CU GEMM ----
// MODE 0: gemm1 (gate_up + GLU epilogue); MODE 1: gemm2 (down proj + bias).
//
// The TLP round: per-block schedule = the proven round-6/8 body (1 barrier
// per tile, counted lgkm, stage-1-ahead, both-sides BK=32 swizzle), but the
// tile is reshaped so TWO blocks fit per CU (48 KB LDS each, 4 waves of
// 256 regs). When one block's waves converge at a barrier and drain LDS
// reads, the co-resident block's waves feed the MFMA pipe (m114/m97 TLP) —
// the overlap all intra-block scheduling attempts (r3,r4,r8,r10,r11)
// failed to create. Per-wave output 128x64, acc=128, frag liveness ~48:
// identical to round 6 -> no spill risk.
template <int MODE>
__global__ __launch_bounds__(256, 2) void gemm4w(
    const unsigned short* __restrict__ A,   // (E,2048,2048) bf16
    const unsigned short* __restrict__ B,   // MODE0: (E,4096,2048); MODE1: (E,2048,2048)
    const float* __restrict__ bias,         // MODE0: (E,4096) interleaved; MODE1: (E,2048)
    void* __restrict__ outv)                // MODE0: act bf16 (E,2048,2048); MODE1: f32 (2048,16,2048)
{
    constexpr int LD = 2048;
    constexpr int BK = 32;
    constexpr int NT = 2048 / BK;           // 64 K-tiles

    __shared__ unsigned short ldsA[2][256 * BK];   // 16 KB per buf
    __shared__ unsigned short ldsB[2][128 * BK];   // 8 KB per buf

    const int t = threadIdx.x, wave = t >> 6, lane = t & 63;
    const int wr = wave >> 1, wc = wave & 1;         // 2M x 2N

    // XCD-aware bijective swizzle (nwg % 8 == 0 for both modes)
    int id = blockIdx.x;
    const int cpx = gridDim.x >> 3;
    id = (id & 7) * cpx + (id >> 3);
    int e, mt, bt;
    if (MODE == 0) { e = id >> 8; mt = (id >> 5) & 7; bt = id & 31; }   // 8 x 32 x 16
    else           { e = id >> 7; mt = (id >> 4) & 7; bt = id & 15; }   // 8 x 16 x 16

    const unsigned short* Aexp = A + ((size_t)e * ROWS + mt * 256) * LD;
    const unsigned short* Bexp = (MODE == 0)
        ? B + (size_t)e * N1 * LD
        : B + ((size_t)e * H_ + bt * 128) * LD;

    ffrag acc[8][4];
#pragma unroll
    for (int i = 0; i < 8; ++i)
#pragma unroll
        for (int j = 0; j < 4; ++j) acc[i][j] = ffrag{0.f, 0.f, 0.f, 0.f};

    // staging: 16B/lane; 16 rows per gload16 (row = 64B at BK=32).
    // swizzle involution s(row) = (row>>1)&3 -> global chunk = (lane&3)^((lane>>3)&3)
    const int rsub = lane >> 2;
    const int csw = ((lane & 3) ^ ((lane >> 3) & 3)) * 8;   // elements

    auto stage = [&](int kt, int b) {
        const int k0 = kt * BK;
        // A: 256 rows / 4 waves = 64 rows = 4 gload16
#pragma unroll
        for (int i = 0; i < 4; ++i) {
            const int Rb = (wave * 4 + i) * 16;
            const int r = Rb + rsub;
            gload16(Aexp + (size_t)r * LD + k0 + csw, (void*)&ldsA[b][Rb * BK]);
        }
        // B: 128 rows / 4 waves = 32 rows = 2 gload16
#pragma unroll
        for (int i = 0; i < 2; ++i) {
            const int Rb = (wave * 2 + i) * 16;
            const int r = Rb + rsub;
            int grow;
            if (MODE == 0)
                grow = ((r >> 5) & 1) * I_ + bt * 64 + (r >> 6) * 32 + (r & 31);
            else
                grow = r;
            gload16(Bexp + (size_t)grow * LD + k0 + csw, (void*)&ldsB[b][Rb * BK]);
        }
    };

    stage(0, 0);

    const int l15 = lane & 15, lr16 = lane >> 4;     // lr16 = k-chunk 0..3
    const int swl = (l15 >> 1) & 3;                  // s(row) for frag rows
    const int kch = (lr16 ^ swl) * 8;                // swizzled k-chunk (elements)
    const int arow0 = wr * 128 + l15;                // A row base
    const int brow0 = wc * 64 + l15;                 // B row base

#pragma unroll 2
    for (int kt = 0; kt < NT; ++kt) {
        const int cur = kt & 1;

        // drain this tile's stage loads (issued one tile ago -> ~free)
        asm volatile("s_waitcnt vmcnt(0)" ::: "memory");
        __builtin_amdgcn_sched_barrier(0);
        block_bar();   // publish buf[cur]; old buffer's reads all retired

        bfrag bB[4], af[8];

        // issue reads: bB (4), af0-3 (4), af4-7 (4)
#pragma unroll
        for (int nf = 0; nf < 4; ++nf)
            bB[nf] = *(const bfrag*)&ldsB[cur][(brow0 + nf * 16) * BK + kch];
#pragma unroll
        for (int mf = 0; mf < 4; ++mf)
            af[mf] = *(const bfrag*)&ldsA[cur][(arow0 + mf * 16) * BK + kch];
        asm volatile("" ::: "memory");   // pin FIFO order
#pragma unroll
        for (int mf = 4; mf < 8; ++mf)
            af[mf] = *(const bfrag*)&ldsA[cur][(arow0 + mf * 16) * BK + kch];

        // prefetch next tile into the other buffer (safe: post-barrier)
        if (kt + 1 < NT) stage(kt + 1, cur ^ 1);

        // blk0: af0-3 x bB (16 MFMA); af4-7's 4 reads drain underneath
        asm volatile("s_waitcnt lgkmcnt(4)" ::: "memory");
        __builtin_amdgcn_sched_barrier(0);
        __builtin_amdgcn_s_setprio(1);
#pragma unroll
        for (int mf = 0; mf < 4; ++mf)
#pragma unroll
            for (int nf = 0; nf < 4; ++nf)
                acc[mf][nf] = __builtin_amdgcn_mfma_f32_16x16x32_bf16(
                    af[mf], bB[nf], acc[mf][nf], 0, 0, 0);
        __builtin_amdgcn_s_setprio(0);

        // blk1: af4-7 x bB (16 MFMA)
        asm volatile("s_waitcnt lgkmcnt(0)" ::: "memory");
        __builtin_amdgcn_sched_barrier(0);
        __builtin_amdgcn_s_setprio(1);
#pragma unroll
        for (int mf = 4; mf < 8; ++mf)
#pragma unroll
            for (int nf = 0; nf < 4; ++nf)
                acc[mf][nf] = __builtin_amdgcn_mfma_f32_16x16x32_bf16(
                    af[mf], bB[nf], acc[mf][nf], 0, 0, 0);
        __builtin_amdgcn_s_setprio(0);
        // no trailing barrier: next tile's top barrier provides it
    }

    // -------- epilogue --------
    const int rb = mt * 256 + wr * 128 + lr16 * 4;
    if (MODE == 0) {
        unsigned short* act = (unsigned short*)outv + (size_t)e * ROWS * I_;
#pragma unroll
        for (int nf = 0; nf < 2; ++nf) {
            const int jj = bt * 64 + wc * 32 + nf * 16 + l15;
            const float gb = bias[(size_t)e * N1 + 2 * jj];
            const float ub = bias[(size_t)e * N1 + 2 * jj + 1];
#pragma unroll
            for (int mf = 0; mf < 8; ++mf)
#pragma unroll
                for (int r = 0; r < 4; ++r) {
                    float g = acc[mf][nf][r] + gb;       // B rows 0-31  = gate
                    float u = acc[mf][2 + nf][r] + ub;   // B rows 32-63 = up (same jj)
                    g = fminf(g, 7.0f);
                    u = fminf(fmaxf(u, -7.0f), 7.0f);
                    const float glu = g / (1.0f + __expf(-1.702f * g));
                    const float av = (u + 1.0f) * glu;
                    act[(size_t)(rb + mf * 16 + r) * I_ + jj] = f2bf(av);
                }
        }
    } else {
        float* out = (float*)outv;
#pragma unroll
        for (int nf = 0; nf < 4; ++nf) {
            const int h = bt * 128 + wc * 64 + nf * 16 + l15;
            const float bb = bias[(size_t)e * H_ + h];
#pragma unroll
            for (int mf = 0; mf < 8; ++mf)
#pragma unroll
                for (int r = 0; r < 4; ++r) {
                    const int row = rb + mf * 16 + r;
                    out[((size_t)row * E_ + e) * H_ + h] = acc[mf][nf][r] + bb;
                }
        }
    }
}

// ---------------- launch ----------------

extern "C" void kernel_launch(void* const* d_in, const int* in_sizes, int n_in,
                              void* d_out, int out_size, void* d_ws, size_t ws_size,
                              hipStream_t stream) {
    const float* disp  = (const float*)d_in[0];
    const float* gup   = (const float*)d_in[1];
    const float* gub   = (const float*)d_in[2];
    const float* down  = (const float*)d_in[3];
    const float* dbias = (const float*)d_in[4];
    float* out = (float*)d_out;

    const size_t NEED = (size_t)512 << 20;
    if (ws_size < NEED) {
        hipMemsetAsync(d_out, 0, (size_t)out_size * sizeof(float), stream);
        return;
    }
    unsigned short* a_bf = (unsigned short*)d_ws;
    unsigned short* b1t  = (unsigned short*)((char*)d_ws + ((size_t)128 << 20));
    unsigned short* b2t  = b1t;  // reused after gemm1 (stream-ordered)
    unsigned short* actb = (unsigned short*)((char*)d_ws + ((size_t)384 << 20));

    convert_a<<<4096, 256, 0, stream>>>(disp, a_bf);
    convert_b1<<<dim3(E_, H_ / 64, N1 / 128), 256, 0, stream>>>(gup, b1t);
    gemm4w<0><<<4096, 256, 0, stream>>>(a_bf, b1t, gub, actb);
    convert_b2<<<dim3(E_, I_ / 64, H_ / 64), 256, 0, stream>>>(down, b2t);
    gemm4w<1><<<2048, 256, 0, stream>>>(actb, b2t, dbias, out);
}

// Round 15
// 1260.478 us; speedup vs baseline: 1.0014x; 1.0014x over previous
//
#include <hip/hip_runtime.h>
#include <stdint.h>

#define DEV __device__ __forceinline__

constexpr int E_ = 16, M_ = 128, H_ = 2048, I_ = 2048;
constexpr int X_ = 16;            // A*B = 2*8
constexpr int N1 = 2 * I_;        // 4096
constexpr int ROWS = X_ * M_;     // 2048 rows per expert

typedef short bfrag __attribute__((ext_vector_type(8)));   // 8 bf16 (4 VGPRs)
typedef float ffrag __attribute__((ext_vector_type(4)));   // MFMA C/D frag
typedef unsigned short us8 __attribute__((ext_vector_type(8)));

DEV unsigned short f2bf(float f) {
    union { float f; unsigned u; } v; v.f = f;
    unsigned u = v.u;
    u += 0x7fffu + ((u >> 16) & 1u);   // RNE
    return (unsigned short)(u >> 16);
}

DEV void gload16(const void* g, void* lds_wave_base) {
    __builtin_amdgcn_global_load_lds(
        (const __attribute__((address_space(1))) unsigned int*)g,
        (__attribute__((address_space(3))) unsigned int*)lds_wave_base,
        16, 0, 0);
}

DEV void block_bar() {
    asm volatile("" ::: "memory");
    __builtin_amdgcn_s_barrier();
    asm volatile("" ::: "memory");
}

// ---------------- converts ----------------

// dispatched (X,E,M,H) f32 -> a_bf (E, X*M, H) bf16  (token-major per expert)
__global__ __launch_bounds__(256) void convert_a(const float* __restrict__ in,
                                                 unsigned short* __restrict__ outb) {
    const int n4 = X_ * E_ * M_ * H_ / 4;
    int idx = blockIdx.x * 256 + threadIdx.x;
    int stride = gridDim.x * 256;
    for (int f = idx; f < n4; f += stride) {
        float4 v = ((const float4*)in)[f];
        ushort4 o;
        o.x = f2bf(v.x); o.y = f2bf(v.y); o.z = f2bf(v.z); o.w = f2bf(v.w);
        const int c = f & 511;          // float4 within row (H/4 = 512)
        const int row = f >> 9;         // (x,e,m) row
        const int m = row & 127, e = (row >> 7) & 15, x = row >> 11;
        ((ushort4*)outb)[((size_t)(e * ROWS + x * M_ + m) << 9) + c] = o;
    }
}

// gate_up (E,H,4096) fp32 -> b1t (E,4096,H) bf16, de-interleaved.
__global__ __launch_bounds__(256) void convert_b1(const float* __restrict__ gup,
                                                  unsigned short* __restrict__ b1t) {
    const int e = blockIdx.x, h0 = blockIdx.y * 64, n0 = blockIdx.z * 128;
    __shared__ float2 tile2[64][64];   // [h-local][n-pair]
    const float* src = gup + (size_t)e * H_ * N1;
    const int t = threadIdx.x;
#pragma unroll
    for (int i = 0; i < 8; ++i) {
        int idx = i * 1024 + t * 4;
        int r = idx >> 7, c = idx & 127;
        float4 v = *(const float4*)(src + (size_t)(h0 + r) * N1 + n0 + c);
        *(float4*)&tile2[r][c >> 1] = v;   // c%4==0 -> 16B aligned
    }
    __syncthreads();
    const int p = t >> 2;          // local output n-row 0..63
    const int hh = (t & 3) * 16;   // 16 h's per thread
    us8 g0, g1, u0, u1;
#pragma unroll
    for (int k = 0; k < 8; ++k) {
        float2 a = tile2[hh + k][p];
        float2 b = tile2[hh + 8 + k][p];
        g0[k] = f2bf(a.x); u0[k] = f2bf(a.y);
        g1[k] = f2bf(b.x); u1[k] = f2bf(b.y);
    }
    unsigned short* dg = b1t + ((size_t)e * N1 + (n0 >> 1) + p) * H_ + h0 + hh;
    unsigned short* du = b1t + ((size_t)e * N1 + I_ + (n0 >> 1) + p) * H_ + h0 + hh;
    *(us8*)dg = g0; *(us8*)(dg + 8) = g1;
    *(us8*)du = u0; *(us8*)(du + 8) = u1;
}

// down (E,I,H) fp32 -> b2t (E,H,I) bf16
__global__ __launch_bounds__(256) void convert_b2(const float* __restrict__ dwn,
                                                  unsigned short* __restrict__ b2t) {
    const int e = blockIdx.x, i0 = blockIdx.y * 64, h0 = blockIdx.z * 64;
    __shared__ float tile[64][65];
    const float* src = dwn + (size_t)e * I_ * H_;
    const int t = threadIdx.x;
#pragma unroll
    for (int it = 0; it < 4; ++it) {
        int idx = it * 1024 + t * 4;
        int r = idx >> 6, c = idx & 63;
        float4 v = *(const float4*)(src + (size_t)(i0 + r) * H_ + h0 + c);
        tile[r][c] = v.x; tile[r][c + 1] = v.y; tile[r][c + 2] = v.z; tile[r][c + 3] = v.w;
    }
    __syncthreads();
    const int hl = t >> 2, ii = (t & 3) * 16;
    us8 o0, o1;
#pragma unroll
    for (int k = 0; k < 8; ++k) {
        o0[k] = f2bf(tile[ii + k][hl]);
        o1[k] = f2bf(tile[ii + 8 + k][hl]);
    }
    unsigned short* d = b2t + ((size_t)e * H_ + h0 + hl) * I_ + i0 + ii;
    *(us8*)d = o0; *(us8*)(d + 8) = o1;
}

// ---- 256x128 4-wave, BK=32, 2-buf, 2-BLOCKS-PER-CU GEMM ----
// MODE 0: gemm1 (gate_up + GLU epilogue); MODE 1: gemm2 (down proj + bias).
//
// The TLP round: per-block schedule = the proven round-6/8 body (1 barrier
// per tile, counted lgkm, stage-1-ahead, both-sides BK=32 swizzle), but the
// tile is reshaped so TWO blocks fit per CU (48 KB LDS each, 4 waves of
// 256 regs). When one block's waves converge at a barrier and drain LDS
// reads, the co-resident block's waves feed the MFMA pipe (m114/m97 TLP) —
// the overlap all intra-block scheduling attempts (r3,r4,r8,r10,r11)
// failed to create. Per-wave output 128x64, acc=128, frag liveness ~48:
// identical to round 6 -> no spill risk.
template <int MODE>
__global__ __launch_bounds__(256, 2) void gemm4w(
    const unsigned short* __restrict__ A,   // (E,2048,2048) bf16
    const unsigned short* __restrict__ B,   // MODE0: (E,4096,2048); MODE1: (E,2048,2048)
    const float* __restrict__ bias,         // MODE0: (E,4096) interleaved; MODE1: (E,2048)
    void* __restrict__ outv)                // MODE0: act bf16 (E,2048,2048); MODE1: f32 (2048,16,2048)
{
    constexpr int LD = 2048;
    constexpr int BK = 32;
    constexpr int NT = 2048 / BK;           // 64 K-tiles

    __shared__ unsigned short ldsA[2][256 * BK];   // 16 KB per buf
    __shared__ unsigned short ldsB[2][128 * BK];   // 8 KB per buf

    const int t = threadIdx.x, wave = t >> 6, lane = t & 63;
    const int wr = wave >> 1, wc = wave & 1;         // 2M x 2N

    // XCD-aware bijective swizzle (nwg % 8 == 0 for both modes)
    int id = blockIdx.x;
    const int cpx = gridDim.x >> 3;
    id = (id & 7) * cpx + (id >> 3);
    int e, mt, bt;
    if (MODE == 0) { e = id >> 8; mt = (id >> 5) & 7; bt = id & 31; }   // 8 x 32 x 16
    else           { e = id >> 7; mt = (id >> 4) & 7; bt = id & 15; }   // 8 x 16 x 16

    const unsigned short* Aexp = A + ((size_t)e * ROWS + mt * 256) * LD;
    const unsigned short* Bexp = (MODE == 0)
        ? B + (size_t)e * N1 * LD
        : B + ((size_t)e * H_ + bt * 128) * LD;

    ffrag acc[8][4];
#pragma unroll
    for (int i = 0; i < 8; ++i)
#pragma unroll
        for (int j = 0; j < 4; ++j) acc[i][j] = ffrag{0.f, 0.f, 0.f, 0.f};

    // staging: 16B/lane; 16 rows per gload16 (row = 64B at BK=32).
    // swizzle involution s(row) = (row>>1)&3 -> global chunk = (lane&3)^((lane>>3)&3)
    const int rsub = lane >> 2;
    const int csw = ((lane & 3) ^ ((lane >> 3) & 3)) * 8;   // elements

    auto stage = [&](int kt, int b) {
        const int k0 = kt * BK;
        // A: 256 rows / 4 waves = 64 rows = 4 gload16
#pragma unroll
        for (int i = 0; i < 4; ++i) {
            const int Rb = (wave * 4 + i) * 16;
            const int r = Rb + rsub;
            gload16(Aexp + (size_t)r * LD + k0 + csw, (void*)&ldsA[b][Rb * BK]);
        }
        // B: 128 rows / 4 waves = 32 rows = 2 gload16
#pragma unroll
        for (int i = 0; i < 2; ++i) {
            const int Rb = (wave * 2 + i) * 16;
            const int r = Rb + rsub;
            int grow;
            if (MODE == 0)
                grow = ((r >> 5) & 1) * I_ + bt * 64 + (r >> 6) * 32 + (r & 31);
            else
                grow = r;
            gload16(Bexp + (size_t)grow * LD + k0 + csw, (void*)&ldsB[b][Rb * BK]);
        }
    };

    stage(0, 0);

    const int l15 = lane & 15, lr16 = lane >> 4;     // lr16 = k-chunk 0..3
    const int swl = (l15 >> 1) & 3;                  // s(row) for frag rows
    const int kch = (lr16 ^ swl) * 8;                // swizzled k-chunk (elements)
    const int arow0 = wr * 128 + l15;                // A row base
    const int brow0 = wc * 64 + l15;                 // B row base

#pragma unroll 2
    for (int kt = 0; kt < NT; ++kt) {
        const int cur = kt & 1;

        // drain this tile's stage loads (issued one tile ago -> ~free)
        asm volatile("s_waitcnt vmcnt(0)" ::: "memory");
        __builtin_amdgcn_sched_barrier(0);
        block_bar();   // publish buf[cur]; old buffer's reads all retired

        bfrag bB[4], af[8];

        // issue reads: bB (4), af0-3 (4), af4-7 (4)
#pragma unroll
        for (int nf = 0; nf < 4; ++nf)
            bB[nf] = *(const bfrag*)&ldsB[cur][(brow0 + nf * 16) * BK + kch];
#pragma unroll
        for (int mf = 0; mf < 4; ++mf)
            af[mf] = *(const bfrag*)&ldsA[cur][(arow0 + mf * 16) * BK + kch];
        asm volatile("" ::: "memory");   // pin FIFO order
#pragma unroll
        for (int mf = 4; mf < 8; ++mf)
            af[mf] = *(const bfrag*)&ldsA[cur][(arow0 + mf * 16) * BK + kch];

        // prefetch next tile into the other buffer (safe: post-barrier)
        if (kt + 1 < NT) stage(kt + 1, cur ^ 1);

        // blk0: af0-3 x bB (16 MFMA); af4-7's 4 reads drain underneath
        asm volatile("s_waitcnt lgkmcnt(4)" ::: "memory");
        __builtin_amdgcn_sched_barrier(0);
        __builtin_amdgcn_s_setprio(1);
#pragma unroll
        for (int mf = 0; mf < 4; ++mf)
#pragma unroll
            for (int nf = 0; nf < 4; ++nf)
                acc[mf][nf] = __builtin_amdgcn_mfma_f32_16x16x32_bf16(
                    af[mf], bB[nf], acc[mf][nf], 0, 0, 0);
        __builtin_amdgcn_s_setprio(0);

        // blk1: af4-7 x bB (16 MFMA)
        asm volatile("s_waitcnt lgkmcnt(0)" ::: "memory");
        __builtin_amdgcn_sched_barrier(0);
        __builtin_amdgcn_s_setprio(1);
#pragma unroll
        for (int mf = 4; mf < 8; ++mf)
#pragma unroll
            for (int nf = 0; nf < 4; ++nf)
                acc[mf][nf] = __builtin_amdgcn_mfma_f32_16x16x32_bf16(
                    af[mf], bB[nf], acc[mf][nf], 0, 0, 0);
        __builtin_amdgcn_s_setprio(0);
        // no trailing barrier: next tile's top barrier provides it
    }

    // -------- epilogue --------
    const int rb = mt * 256 + wr * 128 + lr16 * 4;
    if (MODE == 0) {
        unsigned short* act = (unsigned short*)outv + (size_t)e * ROWS * I_;
#pragma unroll
        for (int nf = 0; nf < 2; ++nf) {
            const int jj = bt * 64 + wc * 32 + nf * 16 + l15;
            const float gb = bias[(size_t)e * N1 + 2 * jj];
            const float ub = bias[(size_t)e * N1 + 2 * jj + 1];
#pragma unroll
            for (int mf = 0; mf < 8; ++mf)
#pragma unroll
                for (int r = 0; r < 4; ++r) {
                    float g = acc[mf][nf][r] + gb;       // B rows 0-31  = gate
                    float u = acc[mf][2 + nf][r] + ub;   // B rows 32-63 = up (same jj)
                    g = fminf(g, 7.0f);
                    u = fminf(fmaxf(u, -7.0f), 7.0f);
                    const float glu = g / (1.0f + __expf(-1.702f * g));
                    const float av = (u + 1.0f) * glu;
                    act[(size_t)(rb + mf * 16 + r) * I_ + jj] = f2bf(av);
                }
        }
    } else {
        float* out = (float*)outv;
#pragma unroll
        for (int nf = 0; nf < 4; ++nf) {
            const int h = bt * 128 + wc * 64 + nf * 16 + l15;
            const float bb = bias[(size_t)e * H_ + h];
#pragma unroll
            for (int mf = 0; mf < 8; ++mf)
#pragma unroll
                for (int r = 0; r < 4; ++r) {
                    const int row = rb + mf * 16 + r;
                    out[((size_t)row * E_ + e) * H_ + h] = acc[mf][nf][r] + bb;
                }
        }
    }
}

// ---------------- launch ----------------

extern "C" void kernel_launch(void* const* d_in, const int* in_sizes, int n_in,
                              void* d_out, int out_size, void* d_ws, size_t ws_size,
                              hipStream_t stream) {
    const float* disp  = (const float*)d_in[0];
    const float* gup   = (const float*)d_in[1];
    const float* gub   = (const float*)d_in[2];
    const float* down  = (const float*)d_in[3];
    const float* dbias = (const float*)d_in[4];
    float* out = (float*)d_out;

    const size_t NEED = (size_t)512 << 20;
    if (ws_size < NEED) {
        hipMemsetAsync(d_out, 0, (size_t)out_size * sizeof(float), stream);
        return;
    }
    unsigned short* a_bf = (unsigned short*)d_ws;
    unsigned short* b1t  = (unsigned short*)((char*)d_ws + ((size_t)128 << 20));
    unsigned short* b2t  = b1t;  // reused after gemm1 (stream-ordered)
    unsigned short* actb = (unsigned short*)((char*)d_ws + ((size_t)384 << 20));

    convert_a<<<4096, 256, 0, stream>>>(disp, a_bf);
    convert_b1<<<dim3(E_, H_ / 64, N1 / 128), 256, 0, stream>>>(gup, b1t);
    gemm4w<0><<<4096, 256, 0, stream>>>(a_bf, b1t, gub, actb);
    convert_b2<<<dim3(E_, I_ / 64, H_ / 64), 256, 0, stream>>>(down, b2t);
    gemm4w<1><<<2048, 256, 0, stream>>>(actb, b2t, dbias, out);
}

// Round 16
// 1162.749 us; speedup vs baseline: 1.0856x; 1.0841x over previous
//
#include <hip/hip_runtime.h>
#include <stdint.h>

#define DEV __device__ __forceinline__

constexpr int E_ = 16, M_ = 128, H_ = 2048, I_ = 2048;
constexpr int X_ = 16;            // A*B = 2*8
constexpr int N1 = 2 * I_;        // 4096
constexpr int ROWS = X_ * M_;     // 2048 rows per expert

typedef short bfrag __attribute__((ext_vector_type(8)));    // 8 bf16 (4 VGPRs)
typedef float f32x16 __attribute__((ext_vector_type(16)));  // 32x32 MFMA C/D
typedef unsigned short us8 __attribute__((ext_vector_type(8)));

DEV unsigned short f2bf(float f) {
    union { float f; unsigned u; } v; v.f = f;
    unsigned u = v.u;
    u += 0x7fffu + ((u >> 16) & 1u);   // RNE
    return (unsigned short)(u >> 16);
}

DEV void gload16(const void* g, void* lds_wave_base) {
    __builtin_amdgcn_global_load_lds(
        (const __attribute__((address_space(1))) unsigned int*)g,
        (__attribute__((address_space(3))) unsigned int*)lds_wave_base,
        16, 0, 0);
}

DEV void block_bar() {
    asm volatile("" ::: "memory");
    __builtin_amdgcn_s_barrier();
    asm volatile("" ::: "memory");
}

// ---------------- converts ----------------

// dispatched (X,E,M,H) f32 -> a_bf (E, X*M, H) bf16  (token-major per expert)
__global__ __launch_bounds__(256) void convert_a(const float* __restrict__ in,
                                                 unsigned short* __restrict__ outb) {
    const int n4 = X_ * E_ * M_ * H_ / 4;
    int idx = blockIdx.x * 256 + threadIdx.x;
    int stride = gridDim.x * 256;
    for (int f = idx; f < n4; f += stride) {
        float4 v = ((const float4*)in)[f];
        ushort4 o;
        o.x = f2bf(v.x); o.y = f2bf(v.y); o.z = f2bf(v.z); o.w = f2bf(v.w);
        const int c = f & 511;          // float4 within row (H/4 = 512)
        const int row = f >> 9;         // (x,e,m) row
        const int m = row & 127, e = (row >> 7) & 15, x = row >> 11;
        ((ushort4*)outb)[((size_t)(e * ROWS + x * M_ + m) << 9) + c] = o;
    }
}

// gate_up (E,H,4096) fp32 -> b1t (E,4096,H) bf16, de-interleaved.
__global__ __launch_bounds__(256) void convert_b1(const float* __restrict__ gup,
                                                  unsigned short* __restrict__ b1t) {
    const int e = blockIdx.x, h0 = blockIdx.y * 64, n0 = blockIdx.z * 128;
    __shared__ float2 tile2[64][64];   // [h-local][n-pair]
    const float* src = gup + (size_t)e * H_ * N1;
    const int t = threadIdx.x;
#pragma unroll
    for (int i = 0; i < 8; ++i) {
        int idx = i * 1024 + t * 4;
        int r = idx >> 7, c = idx & 127;
        float4 v = *(const float4*)(src + (size_t)(h0 + r) * N1 + n0 + c);
        *(float4*)&tile2[r][c >> 1] = v;   // c%4==0 -> 16B aligned
    }
    __syncthreads();
    const int p = t >> 2;          // local output n-row 0..63
    const int hh = (t & 3) * 16;   // 16 h's per thread
    us8 g0, g1, u0, u1;
#pragma unroll
    for (int k = 0; k < 8; ++k) {
        float2 a = tile2[hh + k][p];
        float2 b = tile2[hh + 8 + k][p];
        g0[k] = f2bf(a.x); u0[k] = f2bf(a.y);
        g1[k] = f2bf(b.x); u1[k] = f2bf(b.y);
    }
    unsigned short* dg = b1t + ((size_t)e * N1 + (n0 >> 1) + p) * H_ + h0 + hh;
    unsigned short* du = b1t + ((size_t)e * N1 + I_ + (n0 >> 1) + p) * H_ + h0 + hh;
    *(us8*)dg = g0; *(us8*)(dg + 8) = g1;
    *(us8*)du = u0; *(us8*)(du + 8) = u1;
}

// down (E,I,H) fp32 -> b2t (E,H,I) bf16
__global__ __launch_bounds__(256) void convert_b2(const float* __restrict__ dwn,
                                                  unsigned short* __restrict__ b2t) {
    const int e = blockIdx.x, i0 = blockIdx.y * 64, h0 = blockIdx.z * 64;
    __shared__ float tile[64][65];
    const float* src = dwn + (size_t)e * I_ * H_;
    const int t = threadIdx.x;
#pragma unroll
    for (int it = 0; it < 4; ++it) {
        int idx = it * 1024 + t * 4;
        int r = idx >> 6, c = idx & 63;
        float4 v = *(const float4*)(src + (size_t)(i0 + r) * H_ + h0 + c);
        tile[r][c] = v.x; tile[r][c + 1] = v.y; tile[r][c + 2] = v.z; tile[r][c + 3] = v.w;
    }
    __syncthreads();
    const int hl = t >> 2, ii = (t & 3) * 16;
    us8 o0, o1;
#pragma unroll
    for (int k = 0; k < 8; ++k) {
        o0[k] = f2bf(tile[ii + k][hl]);
        o1[k] = f2bf(tile[ii + 8 + k][hl]);
    }
    unsigned short* d = b2t + ((size_t)e * H_ + h0 + hl) * I_ + i0 + ii;
    *(us8*)d = o0; *(us8*)(d + 8) = o1;
}

// ---- 256x256 8-wave, BK=64, 2-buf, free-run GEMM — 32x32x16 MFMA ----
// MODE 0: gemm1 (gate_up + GLU epilogue); MODE 1: gemm2 (down proj + bias).
//
// Round-6 schedule verbatim (1 barrier/tile, counted lgkm, stage-1-ahead,
// free-run); the ONLY change is the MFMA shape: 32x32x16 runs at the
// 2382-2495 TF ceiling vs 16x16x32's 2075 (m06/m119) and halves the MFMA
// instruction count -> per-tile MFMA floor 2483 -> ~2066 cyc.
// Per wave: output 128x64 = 4(M) x 2(N) tiles of 32x32; acc = 8 x f32x16
// = 128 AGPR (same); 24 ds_read_b128/tile (same bytes).
// Read swizzle re-derived for 32-row frags: global chunk g = ks*2+(lane>>5),
// LDS chunk = g ^ (lane&7)  [stage stores LDS[r][c] = G[r][c^(r&7)], and
// frag rows have r&7 == lane&7]. Bank-balanced: 8 lanes per bank-quad.
// C/D layout (m74/m101 HW-verified): col=lane&31,
// row = (reg&3) + 8*(reg>>2) + 4*(lane>>5).
template <int MODE>
__global__ __launch_bounds__(512, 2) void gemm8p(
    const unsigned short* __restrict__ A,   // (E,2048,2048) bf16
    const unsigned short* __restrict__ B,   // MODE0: (E,4096,2048); MODE1: (E,2048,2048)
    const float* __restrict__ bias,         // MODE0: (E,4096) interleaved; MODE1: (E,2048)
    void* __restrict__ outv)                // MODE0: act bf16 (E,2048,2048); MODE1: f32 (2048,16,2048)
{
    constexpr int LD = 2048;
    constexpr int NT = 2048 / 64;           // 32 K-tiles

    __shared__ unsigned short lds[2][2][256 * 64];   // [buf][A/B][row*64+k]

    const int t = threadIdx.x, wave = t >> 6, lane = t & 63;
    const int wr = wave >> 2, wc = wave & 3;         // 2M x 4N

    // XCD-aware bijective swizzle (nwg % 8 == 0 for both modes)
    int id = blockIdx.x;
    const int cpx = gridDim.x >> 3;
    id = (id & 7) * cpx + (id >> 3);
    int e, mt, bt;
    if (MODE == 0) { e = id >> 7; mt = (id >> 4) & 7; bt = id & 15; }
    else           { e = id >> 6; mt = (id >> 3) & 7; bt = id & 7; }

    const unsigned short* Aexp = A + ((size_t)e * ROWS + mt * 256) * LD;
    const unsigned short* Bexp = (MODE == 0)
        ? B + (size_t)e * N1 * LD
        : B + ((size_t)e * H_ + bt * 256) * LD;

    f32x16 acc[4][2];
#pragma unroll
    for (int i = 0; i < 4; ++i)
#pragma unroll
        for (int j = 0; j < 2; ++j)
#pragma unroll
            for (int r = 0; r < 16; ++r) acc[i][j][r] = 0.f;

    const int rsub = lane >> 3;
    const int csw = ((lane & 7) ^ (lane >> 3)) * 8;  // inverse-swizzled k-chunk (elements)

    auto stage = [&](int kt, int b) {
        const int k0 = kt * 64;
#pragma unroll
        for (int i = 0; i < 4; ++i) {
            const int Rb = (wave * 4 + i) * 8;
            const int r = Rb + rsub;
            gload16(Aexp + (size_t)r * LD + k0 + csw, (void*)&lds[b][0][Rb * 64]);
        }
#pragma unroll
        for (int i = 0; i < 4; ++i) {
            const int Rb = (wave * 4 + i) * 8;
            const int r = Rb + rsub;
            int grow;
            if (MODE == 0)
                grow = ((r >> 5) & 1) * I_ + bt * 128 + (r >> 6) * 32 + (r & 31);
            else
                grow = r;
            gload16(Bexp + (size_t)grow * LD + k0 + csw, (void*)&lds[b][1][Rb * 64]);
        }
    };

    stage(0, 0);

    const int l31 = lane & 31, lr32 = lane >> 5, l7 = lane & 7;
    const int arow0 = wr * 128 + l31;       // A row base for this wave/lane
    const int brow0 = wc * 64 + l31;        // B row base

    // LDS element index of frag (row base rb_, kstep ks_):
    //   (rb_)*64 + (((ks_*2 + lr32) ^ l7) * 8)
#define AIDX(MT_, KS_) ((arow0 + (MT_) * 32) * 64 + ((((KS_) * 2 + lr32) ^ l7) * 8))
#define BIDX(NT_, KS_) ((brow0 + (NT_) * 32) * 64 + ((((KS_) * 2 + lr32) ^ l7) * 8))

#pragma unroll 2
    for (int kt = 0; kt < NT; ++kt) {
        const int cur = kt & 1;

        // drain this tile's stage loads (issued one tile ago -> ~free)
        asm volatile("s_waitcnt vmcnt(0)" ::: "memory");
        __builtin_amdgcn_sched_barrier(0);
        block_bar();   // publish buf[cur]; old buffer's reads all retired

        bfrag bK[2][2], aK0[4], aK1[4];

        // group 1: B ks0/ks1 (4 reads), A ks0 (4 reads)
#pragma unroll
        for (int nt = 0; nt < 2; ++nt)
#pragma unroll
            for (int ks = 0; ks < 2; ++ks)
                bK[nt][ks] = *(const bfrag*)&lds[cur][1][BIDX(nt, ks)];
#pragma unroll
        for (int mt_i = 0; mt_i < 4; ++mt_i)
            aK0[mt_i] = *(const bfrag*)&lds[cur][0][AIDX(mt_i, 0)];
        asm volatile("" ::: "memory");   // pin FIFO order
        // group 2: A ks1 (4 reads)
#pragma unroll
        for (int mt_i = 0; mt_i < 4; ++mt_i)
            aK1[mt_i] = *(const bfrag*)&lds[cur][0][AIDX(mt_i, 1)];

        // prefetch next tile into the other buffer (safe: post-barrier)
        if (kt + 1 < NT) stage(kt + 1, cur ^ 1);

        // ks0: needs bK + aK0 -> allow aK1's 4 outstanding
        asm volatile("s_waitcnt lgkmcnt(4)" ::: "memory");
        __builtin_amdgcn_sched_barrier(0);
        __builtin_amdgcn_s_setprio(1);
#pragma unroll
        for (int mt_i = 0; mt_i < 4; ++mt_i)
#pragma unroll
            for (int nt = 0; nt < 2; ++nt)
                acc[mt_i][nt] = __builtin_amdgcn_mfma_f32_32x32x16_bf16(
                    aK0[mt_i], bK[nt][0], acc[mt_i][nt], 0, 0, 0);
        __builtin_amdgcn_s_setprio(0);

        // ks1
        asm volatile("s_waitcnt lgkmcnt(0)" ::: "memory");
        __builtin_amdgcn_sched_barrier(0);
        __builtin_amdgcn_s_setprio(1);
#pragma unroll
        for (int mt_i = 0; mt_i < 4; ++mt_i)
#pragma unroll
            for (int nt = 0; nt < 2; ++nt)
                acc[mt_i][nt] = __builtin_amdgcn_mfma_f32_32x32x16_bf16(
                    aK1[mt_i], bK[nt][1], acc[mt_i][nt], 0, 0, 0);
        __builtin_amdgcn_s_setprio(0);

        // group 3: B ks2/ks3 (4), A ks2 (4); group 4: A ks3 (4)
        bfrag bL[2][2], aK2[4], aK3[4];
#pragma unroll
        for (int nt = 0; nt < 2; ++nt)
#pragma unroll
            for (int ks = 0; ks < 2; ++ks)
                bL[nt][ks] = *(const bfrag*)&lds[cur][1][BIDX(nt, 2 + ks)];
#pragma unroll
        for (int mt_i = 0; mt_i < 4; ++mt_i)
            aK2[mt_i] = *(const bfrag*)&lds[cur][0][AIDX(mt_i, 2)];
        asm volatile("" ::: "memory");   // pin FIFO order
#pragma unroll
        for (int mt_i = 0; mt_i < 4; ++mt_i)
            aK3[mt_i] = *(const bfrag*)&lds[cur][0][AIDX(mt_i, 3)];

        // ks2: needs bL + aK2 -> allow aK3's 4 outstanding
        asm volatile("s_waitcnt lgkmcnt(4)" ::: "memory");
        __builtin_amdgcn_sched_barrier(0);
        __builtin_amdgcn_s_setprio(1);
#pragma unroll
        for (int mt_i = 0; mt_i < 4; ++mt_i)
#pragma unroll
            for (int nt = 0; nt < 2; ++nt)
                acc[mt_i][nt] = __builtin_amdgcn_mfma_f32_32x32x16_bf16(
                    aK2[mt_i], bL[nt][0], acc[mt_i][nt], 0, 0, 0);
        __builtin_amdgcn_s_setprio(0);

        // ks3
        asm volatile("s_waitcnt lgkmcnt(0)" ::: "memory");
        __builtin_amdgcn_sched_barrier(0);
        __builtin_amdgcn_s_setprio(1);
#pragma unroll
        for (int mt_i = 0; mt_i < 4; ++mt_i)
#pragma unroll
            for (int nt = 0; nt < 2; ++nt)
                acc[mt_i][nt] = __builtin_amdgcn_mfma_f32_32x32x16_bf16(
                    aK3[mt_i], bL[nt][1], acc[mt_i][nt], 0, 0, 0);
        __builtin_amdgcn_s_setprio(0);
        // no trailing barrier: next tile's top barrier provides it
    }
#undef AIDX
#undef BIDX

    // -------- epilogue (32x32 C/D: col=lane&31, row=(reg&3)+8*(reg>>2)+4*(lane>>5)) --------
    const int rb = mt * 256 + wr * 128;
    if (MODE == 0) {
        unsigned short* act = (unsigned short*)outv + (size_t)e * ROWS * I_;
        const int jj = bt * 128 + wc * 32 + l31;
        const float gb = bias[(size_t)e * N1 + 2 * jj];
        const float ub = bias[(size_t)e * N1 + 2 * jj + 1];
#pragma unroll
        for (int mt_i = 0; mt_i < 4; ++mt_i) {
#pragma unroll
            for (int reg = 0; reg < 16; ++reg) {
                const int row = rb + mt_i * 32 + (reg & 3) + 8 * (reg >> 2) + 4 * lr32;
                float g = acc[mt_i][0][reg] + gb;   // nt0 = gate rows
                float u = acc[mt_i][1][reg] + ub;   // nt1 = up rows (same jj)
                g = fminf(g, 7.0f);
                u = fminf(fmaxf(u, -7.0f), 7.0f);
                const float glu = g / (1.0f + __expf(-1.702f * g));
                const float av = (u + 1.0f) * glu;
                act[(size_t)row * I_ + jj] = f2bf(av);
            }
        }
    } else {
        float* out = (float*)outv;
#pragma unroll
        for (int nt = 0; nt < 2; ++nt) {
            const int h = bt * 256 + wc * 64 + nt * 32 + l31;
            const float bb = bias[(size_t)e * H_ + h];
#pragma unroll
            for (int mt_i = 0; mt_i < 4; ++mt_i) {
#pragma unroll
                for (int reg = 0; reg < 16; ++reg) {
                    const int row = rb + mt_i * 32 + (reg & 3) + 8 * (reg >> 2) + 4 * lr32;
                    out[((size_t)row * E_ + e) * H_ + h] = acc[mt_i][nt][reg] + bb;
                }
            }
        }
    }
}

// ---------------- launch ----------------

extern "C" void kernel_launch(void* const* d_in, const int* in_sizes, int n_in,
                              void* d_out, int out_size, void* d_ws, size_t ws_size,
                              hipStream_t stream) {
    const float* disp  = (const float*)d_in[0];
    const float* gup   = (const float*)d_in[1];
    const float* gub   = (const float*)d_in[2];
    const float* down  = (const float*)d_in[3];
    const float* dbias = (const float*)d_in[4];
    float* out = (float*)d_out;

    const size_t NEED = (size_t)512 << 20;
    if (ws_size < NEED) {
        hipMemsetAsync(d_out, 0, (size_t)out_size * sizeof(float), stream);
        return;
    }
    unsigned short* a_bf = (unsigned short*)d_ws;
    unsigned short* b1t  = (unsigned short*)((char*)d_ws + ((size_t)128 << 20));
    unsigned short* b2t  = b1t;  // reused after gemm1 (stream-ordered)
    unsigned short* actb = (unsigned short*)((char*)d_ws + ((size_t)384 << 20));

    convert_a<<<4096, 256, 0, stream>>>(disp, a_bf);
    convert_b1<<<dim3(E_, H_ / 64, N1 / 128), 256, 0, stream>>>(gup, b1t);
    gemm8p<0><<<2048, 512, 0, stream>>>(a_bf, b1t, gub, actb);
    convert_b2<<<dim3(E_, I_ / 64, H_ / 64), 256, 0, stream>>>(down, b2t);
    gemm8p<1><<<1024, 512, 0, stream>>>(actb, b2t, dbias, out);
}

// Round 17
// 1111.503 us; speedup vs baseline: 1.1357x; 1.0461x over previous
//
#include <hip/hip_runtime.h>
#include <stdint.h>

#define DEV __device__ __forceinline__

constexpr int E_ = 16, M_ = 128, H_ = 2048, I_ = 2048;
constexpr int X_ = 16;            // A*B = 2*8
constexpr int N1 = 2 * I_;        // 4096
constexpr int ROWS = X_ * M_;     // 2048 rows per expert

typedef short bfrag __attribute__((ext_vector_type(8)));   // 8 bf16 (4 VGPRs)
typedef float ffrag __attribute__((ext_vector_type(4)));   // MFMA C/D frag
typedef unsigned short us8 __attribute__((ext_vector_type(8)));

DEV unsigned short f2bf(float f) {
    union { float f; unsigned u; } v; v.f = f;
    unsigned u = v.u;
    u += 0x7fffu + ((u >> 16) & 1u);   // RNE
    return (unsigned short)(u >> 16);
}

DEV void gload16(const void* g, void* lds_wave_base) {
    __builtin_amdgcn_global_load_lds(
        (const __attribute__((address_space(1))) unsigned int*)g,
        (__attribute__((address_space(3))) unsigned int*)lds_wave_base,
        16, 0, 0);
}

DEV void block_bar() {
    asm volatile("" ::: "memory");
    __builtin_amdgcn_s_barrier();
    asm volatile("" ::: "memory");
}

// ---------------- converts ----------------

// dispatched (X,E,M,H) f32 -> a_bf (E, X*M, H) bf16  (token-major per expert)
__global__ __launch_bounds__(256) void convert_a(const float* __restrict__ in,
                                                 unsigned short* __restrict__ outb) {
    const int n4 = X_ * E_ * M_ * H_ / 4;
    int idx = blockIdx.x * 256 + threadIdx.x;
    int stride = gridDim.x * 256;
    for (int f = idx; f < n4; f += stride) {
        float4 v = ((const float4*)in)[f];
        ushort4 o;
        o.x = f2bf(v.x); o.y = f2bf(v.y); o.z = f2bf(v.z); o.w = f2bf(v.w);
        const int c = f & 511;          // float4 within row (H/4 = 512)
        const int row = f >> 9;         // (x,e,m) row
        const int m = row & 127, e = (row >> 7) & 15, x = row >> 11;
        ((ushort4*)outb)[((size_t)(e * ROWS + x * M_ + m) << 9) + c] = o;
    }
}

// gate_up (E,H,4096) fp32 -> b1t (E,4096,H) bf16, de-interleaved.
__global__ __launch_bounds__(256) void convert_b1(const float* __restrict__ gup,
                                                  unsigned short* __restrict__ b1t) {
    const int e = blockIdx.x, h0 = blockIdx.y * 64, n0 = blockIdx.z * 128;
    __shared__ float2 tile2[64][64];   // [h-local][n-pair]
    const float* src = gup + (size_t)e * H_ * N1;
    const int t = threadIdx.x;
#pragma unroll
    for (int i = 0; i < 8; ++i) {
        int idx = i * 1024 + t * 4;
        int r = idx >> 7, c = idx & 127;
        float4 v = *(const float4*)(src + (size_t)(h0 + r) * N1 + n0 + c);
        *(float4*)&tile2[r][c >> 1] = v;   // c%4==0 -> 16B aligned
    }
    __syncthreads();
    const int p = t >> 2;          // local output n-row 0..63
    const int hh = (t & 3) * 16;   // 16 h's per thread
    us8 g0, g1, u0, u1;
#pragma unroll
    for (int k = 0; k < 8; ++k) {
        float2 a = tile2[hh + k][p];
        float2 b = tile2[hh + 8 + k][p];
        g0[k] = f2bf(a.x); u0[k] = f2bf(a.y);
        g1[k] = f2bf(b.x); u1[k] = f2bf(b.y);
    }
    unsigned short* dg = b1t + ((size_t)e * N1 + (n0 >> 1) + p) * H_ + h0 + hh;
    unsigned short* du = b1t + ((size_t)e * N1 + I_ + (n0 >> 1) + p) * H_ + h0 + hh;
    *(us8*)dg = g0; *(us8*)(dg + 8) = g1;
    *(us8*)du = u0; *(us8*)(du + 8) = u1;
}

// down (E,I,H) fp32 -> b2t (E,H,I) bf16
__global__ __launch_bounds__(256) void convert_b2(const float* __restrict__ dwn,
                                                  unsigned short* __restrict__ b2t) {
    const int e = blockIdx.x, i0 = blockIdx.y * 64, h0 = blockIdx.z * 64;
    __shared__ float tile[64][65];
    const float* src = dwn + (size_t)e * I_ * H_;
    const int t = threadIdx.x;
#pragma unroll
    for (int it = 0; it < 4; ++it) {
        int idx = it * 1024 + t * 4;
        int r = idx >> 6, c = idx & 63;
        float4 v = *(const float4*)(src + (size_t)(i0 + r) * H_ + h0 + c);
        tile[r][c] = v.x; tile[r][c + 1] = v.y; tile[r][c + 2] = v.z; tile[r][c + 3] = v.w;
    }
    __syncthreads();
    const int hl = t >> 2, ii = (t & 3) * 16;
    us8 o0, o1;
#pragma unroll
    for (int k = 0; k < 8; ++k) {
        o0[k] = f2bf(tile[ii + k][hl]);
        o1[k] = f2bf(tile[ii + 8 + k][hl]);
    }
    unsigned short* d = b2t + ((size_t)e * H_ + h0 + hl) * I_ + i0 + ii;
    *(us8*)d = o0; *(us8*)(d + 8) = o1;
}

// ---- 256x256 8-wave, BK=64: m201-style 4-phase/tile, spread half-tile staging ----
// MODE 0: gemm1 (gate_up + GLU epilogue); MODE 1: gemm2 (down proj + bias).
//
// Per tile kt (buf cur=kt&1), 4 phases, each {reads; stage 1 half (2 gloads);
// bar; lgkm(0); setprio1; 16 MFMA; setprio0; bar}:
//   p0: read bB0(4)+af(8) [lgkm(8)]; stage A-half0(kt+1)->cur^1 ; Q00
//   p1: read bB1(4);                 stage A-half1(kt+1)->cur^1 ; Q01
//   p2: read ag(8);                  stage B-half0(kt+2)->cur   ; Q11
//   p3: (no reads);                  stage B-half1(kt+2)->cur   ; Q10
//        then vmcnt(4) [counted, never 0 mid-loop] before the final barrier.
// Safety: A(kt+1) targets buf(kt+1)=buf(kt-1), fully consumed at end of kt-1;
// B(kt+2) targets buf(kt)'s B region, consumed after p1 (bB0@p0, bB1@p1,
// lgkm(0) + end-barriers make it block-wide). FIFO: vmcnt(4) at p3 keeps
// exactly B(kt+2)'s 4 loads in flight and drains all of tile kt+1's data.
// Swizzle, read patterns, register profile (peak 64 frag VGPRs) = round-6
// (proven 0-conflict, no spill). This adds m196/m218's levers: per-phase
// ds_read ∥ G-load ∥ MFMA interleave + counted vmcnt.
template <int MODE>
__global__ __launch_bounds__(512, 2) void gemm8p(
    const unsigned short* __restrict__ A,   // (E,2048,2048) bf16
    const unsigned short* __restrict__ B,   // MODE0: (E,4096,2048); MODE1: (E,2048,2048)
    const float* __restrict__ bias,         // MODE0: (E,4096) interleaved; MODE1: (E,2048)
    void* __restrict__ outv)                // MODE0: act bf16 (E,2048,2048); MODE1: f32 (2048,16,2048)
{
    constexpr int LD = 2048;
    constexpr int NT = 2048 / 64;           // 32 K-tiles

    __shared__ unsigned short lds[2][2][256 * 64];   // [buf][A/B][row*64+k]

    const int t = threadIdx.x, wave = t >> 6, lane = t & 63;
    const int wr = wave >> 2, wc = wave & 3;         // 2M x 4N

    // XCD-aware bijective swizzle (nwg % 8 == 0 for both modes)
    int id = blockIdx.x;
    const int cpx = gridDim.x >> 3;
    id = (id & 7) * cpx + (id >> 3);
    int e, mt, bt;
    if (MODE == 0) { e = id >> 7; mt = (id >> 4) & 7; bt = id & 15; }
    else           { e = id >> 6; mt = (id >> 3) & 7; bt = id & 7; }

    const unsigned short* Aexp = A + ((size_t)e * ROWS + mt * 256) * LD;
    const unsigned short* Bexp = (MODE == 0)
        ? B + (size_t)e * N1 * LD
        : B + ((size_t)e * H_ + bt * 256) * LD;

    ffrag acc[8][4];
#pragma unroll
    for (int i = 0; i < 8; ++i)
#pragma unroll
        for (int j = 0; j < 4; ++j) acc[i][j] = ffrag{0.f, 0.f, 0.f, 0.f};

    const int rsub = lane >> 3;
    const int csw = ((lane & 7) ^ (lane >> 3)) * 8;  // inverse-swizzled k-chunk (elements)

    // one half-tile of one operand = 128 rows x 64 k = 2 gloads/wave
    auto stageA = [&](int kt, int b, int half) {
        const int k0 = kt * 64;
#pragma unroll
        for (int i = 0; i < 2; ++i) {
            const int Rb = half * 128 + (wave * 2 + i) * 8;
            const int r = Rb + rsub;
            gload16(Aexp + (size_t)r * LD + k0 + csw, (void*)&lds[b][0][Rb * 64]);
        }
    };
    auto stageB = [&](int kt, int b, int half) {
        const int k0 = kt * 64;
#pragma unroll
        for (int i = 0; i < 2; ++i) {
            const int Rb = half * 128 + (wave * 2 + i) * 8;
            const int r = Rb + rsub;
            int grow;
            if (MODE == 0)
                grow = ((r >> 5) & 1) * I_ + bt * 128 + (r >> 6) * 32 + (r & 31);
            else
                grow = r;
            gload16(Bexp + (size_t)grow * LD + k0 + csw, (void*)&lds[b][1][Rb * 64]);
        }
    };

    // -------- prologue: tile0 full + B halves of tile1; vmcnt(4) keeps B(1) in flight --------
    stageA(0, 0, 0); stageA(0, 0, 1);
    stageB(0, 0, 0); stageB(0, 0, 1);
    stageB(1, 1, 0); stageB(1, 1, 1);
    asm volatile("s_waitcnt vmcnt(4)" ::: "memory");
    __builtin_amdgcn_sched_barrier(0);
    block_bar();

    const int l15 = lane & 15, lr16 = lane >> 4, sw = lane & 7;
    const int arow0 = wr * 128 + l15;       // A row base for this wave/lane
    const int brow0 = wc * 64 + l15;        // B row base

    for (int kt = 0; kt < NT; ++kt) {
        const int cur = kt & 1;
        bfrag bB0[2][2], bB1[2][2], af[4][2], ag[4][2];

        // ---- p0: read bB0(4) + af(8); stage A-half0(kt+1); Q00 ----
#pragma unroll
        for (int nf = 0; nf < 2; ++nf)
#pragma unroll
            for (int ks = 0; ks < 2; ++ks)
                bB0[nf][ks] = *(const bfrag*)&lds[cur][1][(brow0 + nf * 16) * 64 + (((ks * 4 + lr16) ^ sw) * 8)];
        asm volatile("" ::: "memory");
#pragma unroll
        for (int mf = 0; mf < 4; ++mf)
#pragma unroll
            for (int ks = 0; ks < 2; ++ks)
                af[mf][ks] = *(const bfrag*)&lds[cur][0][(arow0 + mf * 16) * 64 + (((ks * 4 + lr16) ^ sw) * 8)];
        if (kt + 1 < NT) stageA(kt + 1, cur ^ 1, 0);
        asm volatile("s_waitcnt lgkmcnt(8)" ::: "memory");
        block_bar();
        asm volatile("s_waitcnt lgkmcnt(0)" ::: "memory");
        __builtin_amdgcn_sched_barrier(0);
        __builtin_amdgcn_s_setprio(1);
#pragma unroll
        for (int mf = 0; mf < 4; ++mf)
#pragma unroll
            for (int nf = 0; nf < 2; ++nf)
#pragma unroll
                for (int ks = 0; ks < 2; ++ks)
                    acc[mf][nf] = __builtin_amdgcn_mfma_f32_16x16x32_bf16(
                        af[mf][ks], bB0[nf][ks], acc[mf][nf], 0, 0, 0);
        __builtin_amdgcn_s_setprio(0);
        block_bar();

        // ---- p1: read bB1(4); stage A-half1(kt+1); Q01 ----
#pragma unroll
        for (int nf = 0; nf < 2; ++nf)
#pragma unroll
            for (int ks = 0; ks < 2; ++ks)
                bB1[nf][ks] = *(const bfrag*)&lds[cur][1][(brow0 + 32 + nf * 16) * 64 + (((ks * 4 + lr16) ^ sw) * 8)];
        if (kt + 1 < NT) stageA(kt + 1, cur ^ 1, 1);
        block_bar();
        asm volatile("s_waitcnt lgkmcnt(0)" ::: "memory");
        __builtin_amdgcn_sched_barrier(0);
        __builtin_amdgcn_s_setprio(1);
#pragma unroll
        for (int mf = 0; mf < 4; ++mf)
#pragma unroll
            for (int nf = 0; nf < 2; ++nf)
#pragma unroll
                for (int ks = 0; ks < 2; ++ks)
                    acc[mf][2 + nf] = __builtin_amdgcn_mfma_f32_16x16x32_bf16(
                        af[mf][ks], bB1[nf][ks], acc[mf][2 + nf], 0, 0, 0);
        __builtin_amdgcn_s_setprio(0);
        block_bar();

        // ---- p2: read ag(8); stage B-half0(kt+2); Q11 ----
#pragma unroll
        for (int mf = 0; mf < 4; ++mf)
#pragma unroll
            for (int ks = 0; ks < 2; ++ks)
                ag[mf][ks] = *(const bfrag*)&lds[cur][0][(arow0 + 64 + mf * 16) * 64 + (((ks * 4 + lr16) ^ sw) * 8)];
        if (kt + 2 < NT) stageB(kt + 2, cur, 0);
        block_bar();
        asm volatile("s_waitcnt lgkmcnt(0)" ::: "memory");
        __builtin_amdgcn_sched_barrier(0);
        __builtin_amdgcn_s_setprio(1);
#pragma unroll
        for (int mf = 0; mf < 4; ++mf)
#pragma unroll
            for (int nf = 0; nf < 2; ++nf)
#pragma unroll
                for (int ks = 0; ks < 2; ++ks)
                    acc[4 + mf][2 + nf] = __builtin_amdgcn_mfma_f32_16x16x32_bf16(
                        ag[mf][ks], bB1[nf][ks], acc[4 + mf][2 + nf], 0, 0, 0);
        __builtin_amdgcn_s_setprio(0);
        block_bar();

        // ---- p3: stage B-half1(kt+2); Q10; counted vmcnt; final barrier ----
        if (kt + 2 < NT) stageB(kt + 2, cur, 1);
        block_bar();
        __builtin_amdgcn_s_setprio(1);
#pragma unroll
        for (int mf = 0; mf < 4; ++mf)
#pragma unroll
            for (int nf = 0; nf < 2; ++nf)
#pragma unroll
                for (int ks = 0; ks < 2; ++ks)
                    acc[4 + mf][nf] = __builtin_amdgcn_mfma_f32_16x16x32_bf16(
                        ag[mf][ks], bB0[nf][ks], acc[4 + mf][nf], 0, 0, 0);
        __builtin_amdgcn_s_setprio(0);
        if (kt + 2 < NT)      { asm volatile("s_waitcnt vmcnt(4)" ::: "memory"); }
        else if (kt + 1 < NT) { asm volatile("s_waitcnt vmcnt(0)" ::: "memory"); }
        __builtin_amdgcn_sched_barrier(0);
        if (kt + 1 < NT) block_bar();
    }

    // -------- epilogue --------
    const int rb = mt * 256 + wr * 128 + lr16 * 4;
    if (MODE == 0) {
        unsigned short* act = (unsigned short*)outv + (size_t)e * ROWS * I_;
#pragma unroll
        for (int nf = 0; nf < 2; ++nf) {
            const int jj = bt * 128 + wc * 32 + nf * 16 + l15;
            const float gb = bias[(size_t)e * N1 + 2 * jj];
            const float ub = bias[(size_t)e * N1 + 2 * jj + 1];
#pragma unroll
            for (int mf = 0; mf < 8; ++mf)
#pragma unroll
                for (int r = 0; r < 4; ++r) {
                    float g = acc[mf][nf][r] + gb;       // B rows 0-31  = gate
                    float u = acc[mf][2 + nf][r] + ub;   // B rows 32-63 = up (same jj)
                    g = fminf(g, 7.0f);
                    u = fminf(fmaxf(u, -7.0f), 7.0f);
                    const float glu = g / (1.0f + __expf(-1.702f * g));
                    const float av = (u + 1.0f) * glu;
                    act[(size_t)(rb + mf * 16 + r) * I_ + jj] = f2bf(av);
                }
        }
    } else {
        float* out = (float*)outv;
#pragma unroll
        for (int nf = 0; nf < 4; ++nf) {
            const int h = bt * 256 + wc * 64 + nf * 16 + l15;
            const float bb = bias[(size_t)e * H_ + h];
#pragma unroll
            for (int mf = 0; mf < 8; ++mf)
#pragma unroll
                for (int r = 0; r < 4; ++r) {
                    const int row = rb + mf * 16 + r;
                    out[((size_t)row * E_ + e) * H_ + h] = acc[mf][nf][r] + bb;
                }
        }
    }
}

// ---------------- launch ----------------

extern "C" void kernel_launch(void* const* d_in, const int* in_sizes, int n_in,
                              void* d_out, int out_size, void* d_ws, size_t ws_size,
                              hipStream_t stream) {
    const float* disp  = (const float*)d_in[0];
    const float* gup   = (const float*)d_in[1];
    const float* gub   = (const float*)d_in[2];
    const float* down  = (const float*)d_in[3];
    const float* dbias = (const float*)d_in[4];
    float* out = (float*)d_out;

    const size_t NEED = (size_t)512 << 20;
    if (ws_size < NEED) {
        hipMemsetAsync(d_out, 0, (size_t)out_size * sizeof(float), stream);
        return;
    }
    unsigned short* a_bf = (unsigned short*)d_ws;
    unsigned short* b1t  = (unsigned short*)((char*)d_ws + ((size_t)128 << 20));
    unsigned short* b2t  = b1t;  // reused after gemm1 (stream-ordered)
    unsigned short* actb = (unsigned short*)((char*)d_ws + ((size_t)384 << 20));

    convert_a<<<4096, 256, 0, stream>>>(disp, a_bf);
    convert_b1<<<dim3(E_, H_ / 64, N1 / 128), 256, 0, stream>>>(gup, b1t);
    gemm8p<0><<<2048, 512, 0, stream>>>(a_bf, b1t, gub, actb);
    convert_b2<<<dim3(E_, I_ / 64, H_ / 64), 256, 0, stream>>>(down, b2t);
    gemm8p<1><<<1024, 512, 0, stream>>>(actb, b2t, dbias, out);
}